// Round 11
// baseline (546.883 us; speedup 1.0000x reference)
//
#include <hip/hip_runtime.h>

typedef unsigned short u16;
typedef __attribute__((ext_vector_type(8))) short bf16x8;
typedef __attribute__((ext_vector_type(4))) float f32x4;

#define N_NODES 10000
#define E_EDGES 160000

__device__ __forceinline__ float b2f(u16 u) {
  union { unsigned i; float f; } c; c.i = ((unsigned)u) << 16; return c.f;
}
__device__ __forceinline__ u16 f2b(float f) {
  union { float f; unsigned i; } c; c.f = f;
  unsigned i = c.i;
  return (u16)((i + 0x7FFFu + ((i >> 16) & 1u)) >> 16);  // RNE
}

// ---------------------------------------------------------------------------
// Dtype detection + canonicalization to bf16 (identity if already bf16).
// ---------------------------------------------------------------------------
__global__ void detect_kernel(const unsigned* __restrict__ w, int* __restrict__ flag) {
  int t = threadIdx.x;  // 64 threads
  int cnt = 0;
  for (int i = t; i < 1024; i += 64) {
    unsigned e = (w[i] >> 7) & 0xFF;
    cnt += (e >= 100 && e <= 145) ? 1 : 0;
  }
  for (int o = 32; o; o >>= 1) cnt += __shfl_xor(cnt, o);
  if (t == 0) *flag = (cnt >= 512) ? 1 : 0;
}
__global__ void canon_kernel(const void* __restrict__ src, u16* __restrict__ dst,
                             int n, const int* __restrict__ flag) {
  int i = blockIdx.x * 256 + threadIdx.x;
  if (i >= n) return;
  if (*flag) dst[i] = ((const u16*)src)[i];
  else       dst[i] = f2b(((const float*)src)[i]);
}
__global__ void canon4_kernel(const void* s0, const void* s1, const void* s2, const void* s3,
                              u16* d0, u16* d1, u16* d2, u16* d3,
                              const int* __restrict__ flag) {
  int tsel = blockIdx.x >> 8;
  int i = (blockIdx.x & 255) * 256 + threadIdx.x;
  const void* s = tsel == 0 ? s0 : tsel == 1 ? s1 : tsel == 2 ? s2 : s3;
  u16* d = tsel == 0 ? d0 : tsel == 1 ? d1 : tsel == 2 ? d2 : d3;
  if (*flag) d[i] = ((const u16*)s)[i];
  else       d[i] = f2b(((const float*)s)[i]);
}
__global__ void canon_small_kernel(const void* s0, const void* s1, const void* s2,
                                   const void* s3, const void* s4, const void* s5,
                                   const void* s6,
                                   u16* d0, u16* d1, u16* d2, u16* d3, u16* d4,
                                   u16* d5, u16* d6, const int* __restrict__ flag) {
  int t = threadIdx.x;  // 256 threads
  int f = *flag;
  const void* srcs[7] = {s0, s1, s2, s3, s4, s5, s6};
  u16* dsts[7] = {d0, d1, d2, d3, d4, d5, d6};
  const int ns[7] = {256, 256, 256, 256, 256, 64, 1};
#pragma unroll
  for (int k = 0; k < 7; ++k) {
    if (t < ns[k]) {
      if (f) dsts[k][t] = ((const u16*)srcs[k])[t];
      else   dsts[k][t] = f2b(((const float*)srcs[k])[t]);
    }
  }
}

// ---------------------------------------------------------------------------
// GEMM core (m97-style): out[row][col] = sum_k A[row][k]*B[col][k], bf16.
// 128x128 tile, BK=64, 4 waves (2x2), each wave 4x4 of 16x16x32 MFMA.
// global_load_lds 16B/lane; XOR chunk swizzle (R5: SQ_LDS_BANK_CONFLICT = 0).
// ---------------------------------------------------------------------------
__device__ __forceinline__ void stage_async(const u16* __restrict__ src, int stride,
                                            int row0, int maxRow, int k0,
                                            u16* lds, int w, int lane) {
  int rsel = lane >> 3;              // row within 8-row group
  int gch = (lane & 7) ^ rsel;       // swizzled global chunk for this slot
#pragma unroll
  for (int i = 0; i < 4; ++i) {
    int rb = (w * 4 + i) * 8;        // 8-row group base (wave-uniform)
    int grow = row0 + rb + rsel;
    grow = grow > maxRow ? maxRow : grow;
    const u16* gp = src + (size_t)grow * stride + k0 + gch * 8;
    u16* lp = lds + rb * 64;         // wave-uniform base; HW adds lane*16B
    __builtin_amdgcn_global_load_lds(
        (const __attribute__((address_space(1))) void*)gp,
        (__attribute__((address_space(3))) void*)lp, 16, 0, 0);
  }
}

__device__ __forceinline__ void mma_tile(const u16* lA, const u16* lB,
                                         f32x4 acc[4][4], int wr, int wc, int lane) {
#pragma unroll
  for (int ks = 0; ks < 2; ++ks) {
    bf16x8 af[4], bfr[4];
    int g = ks * 4 + (lane >> 4);
#pragma unroll
    for (int t = 0; t < 4; ++t) {
      int rowA = wr * 64 + t * 16 + (lane & 15);
      af[t] = *(const bf16x8*)(lA + rowA * 64 + ((g ^ (rowA & 7)) * 8));
      int rowB = wc * 64 + t * 16 + (lane & 15);
      bfr[t] = *(const bf16x8*)(lB + rowB * 64 + ((g ^ (rowB & 7)) * 8));
    }
#pragma unroll
    for (int ti = 0; ti < 4; ++ti)
#pragma unroll
      for (int tj = 0; tj < 4; ++tj)
        acc[ti][tj] = __builtin_amdgcn_mfma_f32_16x16x32_bf16(af[ti], bfr[tj],
                                                              acc[ti][tj], 0, 0, 0);
  }
}

template <bool RELU, bool F32OUT>
__global__ __launch_bounds__(256, 2)
void gemm_kernel(const u16* __restrict__ A, const u16* __restrict__ B,
                 const u16* __restrict__ bias, float* __restrict__ outF,
                 u16* __restrict__ outB, int NN, int J, int K) {
  __shared__ u16 lA[128 * 64];
  __shared__ u16 lB[128 * 64];
  int lane = threadIdx.x & 63;
  int w = threadIdx.x >> 6;
  int wr = w >> 1, wc = w & 1;
  int n0 = blockIdx.y * 128;
  int j0 = blockIdx.x * 128;
  f32x4 acc[4][4];
#pragma unroll
  for (int i = 0; i < 4; ++i)
#pragma unroll
    for (int j = 0; j < 4; ++j) acc[i][j] = (f32x4){0.f, 0.f, 0.f, 0.f};

  for (int kt = 0; kt < K; kt += 64) {
    stage_async(A, K, n0, NN - 1, kt, lA, w, lane);
    stage_async(B, K, j0, J - 1, kt, lB, w, lane);
    __syncthreads();
    mma_tile(lA, lB, acc, wr, wc, lane);
    __syncthreads();
  }

  // C/D layout (m89-verified): col = lane&15, row = (lane>>4)*4 + reg
#pragma unroll
  for (int ti = 0; ti < 4; ++ti)
#pragma unroll
    for (int tj = 0; tj < 4; ++tj) {
      int col = j0 + wc * 64 + tj * 16 + (lane & 15);
      float bv = bias ? b2f(bias[col]) : 0.0f;
#pragma unroll
      for (int r = 0; r < 4; ++r) {
        int row = n0 + wr * 64 + ti * 16 + ((lane >> 4) << 2) + r;
        if (row < NN) {
          float v = acc[ti][tj][r] + bv;
          if (RELU) v = fmaxf(v, 0.0f);
          if (F32OUT) outF[(size_t)row * J + col] = v;
          else        outB[(size_t)row * J + col] = f2b(v);
        }
      }
    }
}

// ---------------------------------------------------------------------------
// Fused lin2+lin3+lin4 (R10-verified): B = [lin2_w ; lin4_w], bias = [b2;b4].
// cols<256: x1 in registers -> dot w3 -> atomic out1acc.  cols>=256: x2 ->
// bf16 x2v.  Grid (4, 79).
// ---------------------------------------------------------------------------
__global__ __launch_bounds__(256, 2)
void gemm_fused234_kernel(const u16* __restrict__ A, const u16* __restrict__ B,
                          const u16* __restrict__ bias, const u16* __restrict__ w3,
                          float* __restrict__ out1acc, u16* __restrict__ x2v, int NN) {
  __shared__ u16 lA[128 * 64];
  __shared__ u16 lB[128 * 64];
  int lane = threadIdx.x & 63;
  int w = threadIdx.x >> 6;
  int wr = w >> 1, wc = w & 1;
  int n0 = blockIdx.y * 128;
  int j0 = blockIdx.x * 128;
  f32x4 acc[4][4];
#pragma unroll
  for (int i = 0; i < 4; ++i)
#pragma unroll
    for (int j = 0; j < 4; ++j) acc[i][j] = (f32x4){0.f, 0.f, 0.f, 0.f};

  for (int kt = 0; kt < 256; kt += 64) {
    stage_async(A, 256, n0, NN - 1, kt, lA, w, lane);
    stage_async(B, 256, j0, 511, kt, lB, w, lane);
    __syncthreads();
    mma_tile(lA, lB, acc, wr, wc, lane);
    __syncthreads();
  }

  if (j0 < 256) {
    float part[4][4];
#pragma unroll
    for (int ti = 0; ti < 4; ++ti)
#pragma unroll
      for (int r = 0; r < 4; ++r) part[ti][r] = 0.0f;
#pragma unroll
    for (int ti = 0; ti < 4; ++ti)
#pragma unroll
      for (int tj = 0; tj < 4; ++tj) {
        int col = j0 + wc * 64 + tj * 16 + (lane & 15);
        float bv = b2f(bias[col]);
        float wv = b2f(w3[col]);
#pragma unroll
        for (int r = 0; r < 4; ++r) {
          float v = fmaxf(acc[ti][tj][r] + bv, 0.0f);
          part[ti][r] += v * wv;
        }
      }
#pragma unroll
    for (int ti = 0; ti < 4; ++ti)
#pragma unroll
      for (int r = 0; r < 4; ++r) {
        float s = part[ti][r];
        s += __shfl_xor(s, 1);
        s += __shfl_xor(s, 2);
        s += __shfl_xor(s, 4);
        s += __shfl_xor(s, 8);
        if ((lane & 15) == 0) {
          int row = n0 + wr * 64 + ti * 16 + ((lane >> 4) << 2) + r;
          if (row < NN) unsafeAtomicAdd(&out1acc[row], s);
        }
      }
  } else {
#pragma unroll
    for (int ti = 0; ti < 4; ++ti)
#pragma unroll
      for (int tj = 0; tj < 4; ++tj) {
        int col = j0 + wc * 64 + tj * 16 + (lane & 15);
        float bv = b2f(bias[col]);
#pragma unroll
        for (int r = 0; r < 4; ++r) {
          int row = n0 + wr * 64 + ti * 16 + ((lane >> 4) << 2) + r;
          if (row < NN) {
            float v = fmaxf(acc[ti][tj][r] + bv, 0.0f);
            x2v[(size_t)row * 256 + (col - 256)] = f2b(v);
          }
        }
      }
  }
}

// ---------------------------------------------------------------------------
// Bilinear v4 (R11): BARRIER-FREE K-loop.  K=256 is small enough that each
// wave loads its own A/B fragments directly global->VGPR (immediate-offset
// loads off 8 row pointers) and runs all 128 MFMAs with no LDS, no barriers,
// no vmcnt(0) drains — the compiler interleaves loads/MFMA with fine-grained
// s_waitcnt vmcnt(N).  2x fragment duplication across waves is L1/L2-absorbed
// (R6: 12x traffic cost only +15%; latency, not BW, binds this kernel).
// Epilogue xv: the two needed x2v k-tiles staged to LDS up front; ONE barrier
// after the K-loop; tile select = wc (mg = m0g + wc*64 + tj*16 + (lane&15)).
// ---------------------------------------------------------------------------
__global__ __launch_bounds__(256, 2)
void bilinear_kernel(const u16* __restrict__ x2v, const u16* __restrict__ W,
                     float* __restrict__ out2acc, int NN) {
  __shared__ u16 lX[2][128 * 64];   // 32 KB: x2v k-tiles m0g/64 and m0g/64+1
  int lane = threadIdx.x & 63;
  int w = threadIdx.x >> 6;
  int wr = w >> 1, wc = w & 1;
  int n0 = blockIdx.y * 128;
  int rm0 = blockIdx.x * 128;
  int m0g = rm0 & 255;

  // stage epilogue x-tiles (async; drained by the single barrier below)
  stage_async(x2v, 256, n0, NN - 1, m0g, lX[0], w, lane);
  stage_async(x2v, 256, n0, NN - 1, m0g + 64, lX[1], w, lane);

  // per-wave fragment row pointers (lane>>4 chunk folded in)
  const u16* pa[4];
  const u16* pb[4];
#pragma unroll
  for (int t = 0; t < 4; ++t) {
    int rowA = n0 + wr * 64 + t * 16 + (lane & 15);
    rowA = rowA > NN - 1 ? NN - 1 : rowA;
    pa[t] = x2v + (size_t)rowA * 256 + ((lane >> 4) * 8);
    int rowB = rm0 + wc * 64 + t * 16 + (lane & 15);
    pb[t] = W + (size_t)rowB * 256 + ((lane >> 4) * 8);
  }

  f32x4 acc[4][4];
#pragma unroll
  for (int i = 0; i < 4; ++i)
#pragma unroll
    for (int j = 0; j < 4; ++j) acc[i][j] = (f32x4){0.f, 0.f, 0.f, 0.f};

#pragma unroll
  for (int kt = 0; kt < 4; ++kt)
#pragma unroll
    for (int ks = 0; ks < 2; ++ks) {
      int k0 = kt * 64 + ks * 32;
      bf16x8 af[4], bfr[4];
#pragma unroll
      for (int t = 0; t < 4; ++t) af[t] = *(const bf16x8*)(pa[t] + k0);
#pragma unroll
      for (int t = 0; t < 4; ++t) bfr[t] = *(const bf16x8*)(pb[t] + k0);
#pragma unroll
      for (int ti = 0; ti < 4; ++ti)
#pragma unroll
        for (int tj = 0; tj < 4; ++tj)
          acc[ti][tj] = __builtin_amdgcn_mfma_f32_16x16x32_bf16(af[ti], bfr[tj],
                                                                acc[ti][tj], 0, 0, 0);
    }

  __syncthreads();   // the ONLY barrier: lX staging complete & visible

  int region = rm0 >> 8;
  float rowsum[4][4];
#pragma unroll
  for (int ti = 0; ti < 4; ++ti)
#pragma unroll
    for (int r = 0; r < 4; ++r) rowsum[ti][r] = 0.0f;

#pragma unroll
  for (int ti = 0; ti < 4; ++ti)
#pragma unroll
    for (int tj = 0; tj < 4; ++tj) {
      int kl = tj * 16 + (lane & 15);        // 0..63 within wave's 64-col half
      int ch = kl >> 3, off = kl & 7;
#pragma unroll
      for (int r = 0; r < 4; ++r) {
        int rowl = wr * 64 + ti * 16 + ((lane >> 4) << 2) + r;
        float xv = b2f(lX[wc][rowl * 64 + ((ch ^ (rowl & 7)) * 8) + off]);
        rowsum[ti][r] += acc[ti][tj][r] * xv;
      }
    }

#pragma unroll
  for (int ti = 0; ti < 4; ++ti)
#pragma unroll
    for (int r = 0; r < 4; ++r) {
      float s = rowsum[ti][r];
      s += __shfl_xor(s, 1);
      s += __shfl_xor(s, 2);
      s += __shfl_xor(s, 4);
      s += __shfl_xor(s, 8);
      if ((lane & 15) == 0) {
        int rowl = wr * 64 + ti * 16 + ((lane >> 4) << 2) + r;
        int n = n0 + rowl;
        if (n < NN) unsafeAtomicAdd(&out2acc[(size_t)n * 64 + region], s);
      }
    }
}

// --------------------- edge sort (counting) + gather ------------------------
__global__ void hist_kernel(const int* __restrict__ ei, int* __restrict__ count) {
  int i = blockIdx.x * 256 + threadIdx.x;
  if (i < E_EDGES) atomicAdd(&count[ei[E_EDGES + i]], 1);
}

// shuffle-based scan: 4 barriers/iter (was 22)
__global__ void scan_kernel(const int* __restrict__ count, int* __restrict__ start,
                            int* __restrict__ cursor, float* __restrict__ dinv) {
  __shared__ int wsum[16];
  __shared__ int carry_s;
  int t = threadIdx.x;          // 1024 threads = 16 waves
  int wv = t >> 6, ln = t & 63;
  if (t == 0) carry_s = 0;
  __syncthreads();
  for (int base = 0; base < N_NODES; base += 1024) {
    int i = base + t;
    int v = (i < N_NODES) ? count[i] : 0;
    int s = v;
#pragma unroll
    for (int o = 1; o < 64; o <<= 1) {
      int u = __shfl_up(s, o);
      if (ln >= o) s += u;
    }
    if (ln == 63) wsum[wv] = s;
    __syncthreads();
    if (wv == 0) {
      int x = (ln < 16) ? wsum[ln] : 0;
#pragma unroll
      for (int o = 1; o < 16; o <<= 1) {
        int u = __shfl_up(x, o);
        if (ln >= o) x += u;
      }
      if (ln < 16) wsum[ln] = x;
    }
    __syncthreads();
    int excl = s - v + (wv ? wsum[wv - 1] : 0) + carry_s;
    if (i < N_NODES) {
      start[i] = excl;
      cursor[i] = excl;
      dinv[i] = rsqrtf(1.0f + (float)v);
    }
    __syncthreads();
    if (t == 0) carry_s += wsum[15];
    __syncthreads();
  }
}

__global__ void place_kernel(const int* __restrict__ ei, int* __restrict__ cursor,
                             int* __restrict__ order) {
  int i = blockIdx.x * 256 + threadIdx.x;
  if (i >= E_EDGES) return;
  int d = ei[E_EDGES + i];
  int pos = atomicAdd(&cursor[d], 1);
  order[pos] = i;
}

__global__ void gather_kernel(const int* __restrict__ ei, const int* __restrict__ order,
                              const int* __restrict__ start, const int* __restrict__ count,
                              const float* __restrict__ dinv, const float* __restrict__ xw,
                              const u16* __restrict__ conv_b, const u16* __restrict__ x,
                              u16* __restrict__ x0) {
  int node = (blockIdx.x * blockDim.x + threadIdx.x) >> 6;
  int lane = threadIdx.x & 63;
  if (node >= N_NODES) return;
  int s0 = start[node], cnt = count[node];
  float dn = dinv[node];
  float ax = 0.f, ay = 0.f, az = 0.f, aw = 0.f;
  for (int base = 0; base < cnt; base += 64) {
    int rem = cnt - base;
    int m = rem < 64 ? rem : 64;
    int eid = (lane < m) ? order[s0 + base + lane] : 0;
    int s = (lane < m) ? ei[eid] : 0;
    float nrm = (lane < m) ? dinv[s] * dn : 0.f;
    for (int j = 0; j < m; ++j) {
      int sj = __shfl(s, j);
      float nj = __shfl(nrm, j);
      float4 v = *((const float4*)(xw + (size_t)sj * 256) + lane);
      ax += nj * v.x; ay += nj * v.y; az += nj * v.z; aw += nj * v.w;
    }
  }
  float4 sv = *((const float4*)(xw + (size_t)node * 256) + lane);
  float slw = dn * dn;
  const u16* bb = conv_b + lane * 4;
  const u16* xr = x + (size_t)node * 256 + lane * 4;
  u16 o[4];
  float vals[4] = {ax + slw * sv.x, ay + slw * sv.y, az + slw * sv.z, aw + slw * sv.w};
#pragma unroll
  for (int j = 0; j < 4; ++j) {
    float v = vals[j] + b2f(bb[j]);
    v = fmaxf(v, 0.0f) + b2f(xr[j]);
    o[j] = f2b(v);
  }
  *((ushort4*)(x0 + (size_t)node * 256) + lane) = make_ushort4(o[0], o[1], o[2], o[3]);
}

// ------------------------------- final output -------------------------------
__global__ void out_final_kernel(const float* __restrict__ out1acc,
                                 const float* __restrict__ out2acc,
                                 const u16* __restrict__ b3, const u16* __restrict__ bb,
                                 void* __restrict__ dout, const int* __restrict__ flag) {
  int idx = blockIdx.x * 256 + threadIdx.x;
  int f = *flag;
  if (idx < N_NODES) {
    float v = out1acc[idx] + b2f(b3[0]);
    if (f) ((u16*)dout)[idx] = f2b(v);
    else   ((float*)dout)[idx] = v;
  } else if (idx < N_NODES + N_NODES * 64) {
    int k = idx - N_NODES;
    float v = out2acc[k] + b2f(bb[k & 63]);
    if (f) ((u16*)dout)[idx] = f2b(v);
    else   ((float*)dout)[idx] = v;
  }
}

// ----------------------------------------------------------------------------
extern "C" void kernel_launch(void* const* d_in, const int* in_sizes, int n_in,
                              void* d_out, int out_size, void* d_ws, size_t ws_size,
                              hipStream_t stream) {
  const int* ei = (const int*)d_in[1];

  float* ws      = (float*)d_ws;
  float* xw      = ws;                          // [N,256] f32
  int*   count   = (int*)(xw + N_NODES * 256);  // [N]
  int*   start   = count + 10240;               // [N]
  int*   cursor  = start + 10240;               // [N]
  int*   order   = cursor + 10240;              // [E]
  float* dinv    = (float*)(order + E_EDGES);   // [N]
  float* out1acc = dinv + 10240;                // [N] (padded 10240)
  float* out2acc = out1acc + 10240;             // [N,64] (adjacent: one memset)
  u16* x0  = (u16*)(out2acc + N_NODES * 64);    // [N,256] bf16
  u16* x0m = x0 + N_NODES * 256;
  u16* x2v = x0m + N_NODES * 256;
  u16* cx  = x2v + N_NODES * 256;               // canonical bf16 inputs
  u16* cwc = cx + N_NODES * 256;
  u16* cw1 = cwc + 65536;
  u16* cw2 = cw1 + 65536;                       // cw2, cw4 contiguous = [512,256]
  u16* cw4 = cw2 + 65536;
  u16* cwB = cw4 + 65536;
  u16* cbc = cwB + 4194304;
  u16* cb1 = cbc + 256;
  u16* cb2 = cb1 + 256;                         // cb2, cb4 contiguous = [512]
  u16* cb4 = cb2 + 256;
  u16* cw3 = cb4 + 256;
  u16* cbB = cw3 + 256;
  u16* cb3 = cbB + 64;
  int* flag = (int*)(cb3 + 16);

  hipMemsetAsync(count, 0, N_NODES * sizeof(int), stream);
  hipMemsetAsync(out1acc, 0, (10240 + (size_t)N_NODES * 64) * sizeof(float), stream);

  detect_kernel<<<1, 64, 0, stream>>>((const unsigned*)d_in[0], flag);

  canon_kernel<<<(N_NODES * 256 + 255) / 256, 256, 0, stream>>>(d_in[0], cx, N_NODES * 256, flag);
  canon4_kernel<<<1024, 256, 0, stream>>>(d_in[2], d_in[4], d_in[6], d_in[10],
                                          cwc, cw1, cw2, cw4, flag);
  canon_small_kernel<<<1, 256, 0, stream>>>(d_in[3], d_in[5], d_in[7], d_in[11],
                                            d_in[8], d_in[13], d_in[9],
                                            cbc, cb1, cb2, cb4, cw3, cbB, cb3, flag);
  canon_kernel<<<(4194304 + 255) / 256, 256, 0, stream>>>(d_in[12], cwB, 4194304, flag);

  hist_kernel<<<(E_EDGES + 255) / 256, 256, 0, stream>>>(ei, count);
  scan_kernel<<<1, 1024, 0, stream>>>(count, start, cursor, dinv);
  place_kernel<<<(E_EDGES + 255) / 256, 256, 0, stream>>>(ei, cursor, order);

  gemm_kernel<false, true><<<dim3(2, 79), 256, 0, stream>>>(
      cx, cwc, nullptr, xw, nullptr, N_NODES, 256, 256);

  gather_kernel<<<(N_NODES * 64 + 255) / 256, 256, 0, stream>>>(
      ei, order, start, count, dinv, xw, cbc, cx, x0);

  gemm_kernel<true, false><<<dim3(2, 79), 256, 0, stream>>>(
      x0, cw1, cb1, nullptr, x0m, N_NODES, 256, 256);

  gemm_fused234_kernel<<<dim3(4, 79), 256, 0, stream>>>(
      x0m, cw2, cb2, cw3, out1acc, x2v, N_NODES);

  bilinear_kernel<<<dim3(128, 79), 256, 0, stream>>>(x2v, cwB, out2acc, N_NODES);

  out_final_kernel<<<(N_NODES * 65 + 255) / 256, 256, 0, stream>>>(
      out1acc, out2acc, cb3, cbB, d_out, flag);
}

// Round 12
// 404.338 us; speedup vs baseline: 1.3525x; 1.3525x over previous
//
#include <hip/hip_runtime.h>

typedef unsigned short u16;
typedef __attribute__((ext_vector_type(8))) short bf16x8;
typedef __attribute__((ext_vector_type(4))) float f32x4;

#define N_NODES 10000
#define E_EDGES 160000

__device__ __forceinline__ float b2f(u16 u) {
  union { unsigned i; float f; } c; c.i = ((unsigned)u) << 16; return c.f;
}
__device__ __forceinline__ u16 f2b(float f) {
  union { float f; unsigned i; } c; c.f = f;
  unsigned i = c.i;
  return (u16)((i + 0x7FFFu + ((i >> 16) & 1u)) >> 16);  // RNE
}

// ---------------------------------------------------------------------------
// Dtype detection + canonicalization to bf16 (identity if already bf16).
// ---------------------------------------------------------------------------
__global__ void detect_kernel(const unsigned* __restrict__ w, int* __restrict__ flag) {
  int t = threadIdx.x;  // 64 threads
  int cnt = 0;
  for (int i = t; i < 1024; i += 64) {
    unsigned e = (w[i] >> 7) & 0xFF;
    cnt += (e >= 100 && e <= 145) ? 1 : 0;
  }
  for (int o = 32; o; o >>= 1) cnt += __shfl_xor(cnt, o);
  if (t == 0) *flag = (cnt >= 512) ? 1 : 0;
}
__global__ void canon_kernel(const void* __restrict__ src, u16* __restrict__ dst,
                             int n, const int* __restrict__ flag) {
  int i = blockIdx.x * 256 + threadIdx.x;
  if (i >= n) return;
  if (*flag) dst[i] = ((const u16*)src)[i];
  else       dst[i] = f2b(((const float*)src)[i]);
}
__global__ void canon4_kernel(const void* s0, const void* s1, const void* s2, const void* s3,
                              u16* d0, u16* d1, u16* d2, u16* d3,
                              const int* __restrict__ flag) {
  int tsel = blockIdx.x >> 8;
  int i = (blockIdx.x & 255) * 256 + threadIdx.x;
  const void* s = tsel == 0 ? s0 : tsel == 1 ? s1 : tsel == 2 ? s2 : s3;
  u16* d = tsel == 0 ? d0 : tsel == 1 ? d1 : tsel == 2 ? d2 : d3;
  if (*flag) d[i] = ((const u16*)s)[i];
  else       d[i] = f2b(((const float*)s)[i]);
}
__global__ void canon_small_kernel(const void* s0, const void* s1, const void* s2,
                                   const void* s3, const void* s4, const void* s5,
                                   const void* s6,
                                   u16* d0, u16* d1, u16* d2, u16* d3, u16* d4,
                                   u16* d5, u16* d6, const int* __restrict__ flag) {
  int t = threadIdx.x;  // 256 threads
  int f = *flag;
  const void* srcs[7] = {s0, s1, s2, s3, s4, s5, s6};
  u16* dsts[7] = {d0, d1, d2, d3, d4, d5, d6};
  const int ns[7] = {256, 256, 256, 256, 256, 64, 1};
#pragma unroll
  for (int k = 0; k < 7; ++k) {
    if (t < ns[k]) {
      if (f) dsts[k][t] = ((const u16*)srcs[k])[t];
      else   dsts[k][t] = f2b(((const float*)srcs[k])[t]);
    }
  }
}

// ---------------------------------------------------------------------------
// GEMM core (m97-style): out[row][col] = sum_k A[row][k]*B[col][k], bf16.
// 128x128 tile, BK=64, 4 waves (2x2), each wave 4x4 of 16x16x32 MFMA.
// global_load_lds 16B/lane; XOR chunk swizzle (R5: SQ_LDS_BANK_CONFLICT = 0).
// R11 lesson: LDS staging is NOT removable — direct global fragment loads
// uncoalesce (lane&15 spans 16 rows) and sink MfmaUtil to 9.7%.
// ---------------------------------------------------------------------------
__device__ __forceinline__ void stage_async(const u16* __restrict__ src, int stride,
                                            int row0, int maxRow, int k0,
                                            u16* lds, int w, int lane) {
  int rsel = lane >> 3;              // row within 8-row group
  int gch = (lane & 7) ^ rsel;       // swizzled global chunk for this slot
#pragma unroll
  for (int i = 0; i < 4; ++i) {
    int rb = (w * 4 + i) * 8;        // 8-row group base (wave-uniform)
    int grow = row0 + rb + rsel;
    grow = grow > maxRow ? maxRow : grow;
    const u16* gp = src + (size_t)grow * stride + k0 + gch * 8;
    u16* lp = lds + rb * 64;         // wave-uniform base; HW adds lane*16B
    __builtin_amdgcn_global_load_lds(
        (const __attribute__((address_space(1))) void*)gp,
        (__attribute__((address_space(3))) void*)lp, 16, 0, 0);
  }
}

__device__ __forceinline__ void mma_tile(const u16* lA, const u16* lB,
                                         f32x4 acc[4][4], int wr, int wc, int lane) {
#pragma unroll
  for (int ks = 0; ks < 2; ++ks) {
    bf16x8 af[4], bfr[4];
    int g = ks * 4 + (lane >> 4);
#pragma unroll
    for (int t = 0; t < 4; ++t) {
      int rowA = wr * 64 + t * 16 + (lane & 15);
      af[t] = *(const bf16x8*)(lA + rowA * 64 + ((g ^ (rowA & 7)) * 8));
      int rowB = wc * 64 + t * 16 + (lane & 15);
      bfr[t] = *(const bf16x8*)(lB + rowB * 64 + ((g ^ (rowB & 7)) * 8));
    }
#pragma unroll
    for (int ti = 0; ti < 4; ++ti)
#pragma unroll
      for (int tj = 0; tj < 4; ++tj)
        acc[ti][tj] = __builtin_amdgcn_mfma_f32_16x16x32_bf16(af[ti], bfr[tj],
                                                              acc[ti][tj], 0, 0, 0);
  }
}

template <bool RELU, bool F32OUT>
__global__ __launch_bounds__(256, 2)
void gemm_kernel(const u16* __restrict__ A, const u16* __restrict__ B,
                 const u16* __restrict__ bias, float* __restrict__ outF,
                 u16* __restrict__ outB, int NN, int J, int K) {
  __shared__ u16 lA[128 * 64];
  __shared__ u16 lB[128 * 64];
  int lane = threadIdx.x & 63;
  int w = threadIdx.x >> 6;
  int wr = w >> 1, wc = w & 1;
  int n0 = blockIdx.y * 128;
  int j0 = blockIdx.x * 128;
  f32x4 acc[4][4];
#pragma unroll
  for (int i = 0; i < 4; ++i)
#pragma unroll
    for (int j = 0; j < 4; ++j) acc[i][j] = (f32x4){0.f, 0.f, 0.f, 0.f};

  for (int kt = 0; kt < K; kt += 64) {
    stage_async(A, K, n0, NN - 1, kt, lA, w, lane);
    stage_async(B, K, j0, J - 1, kt, lB, w, lane);
    __syncthreads();
    mma_tile(lA, lB, acc, wr, wc, lane);
    __syncthreads();
  }

  // C/D layout (m89-verified): col = lane&15, row = (lane>>4)*4 + reg
#pragma unroll
  for (int ti = 0; ti < 4; ++ti)
#pragma unroll
    for (int tj = 0; tj < 4; ++tj) {
      int col = j0 + wc * 64 + tj * 16 + (lane & 15);
      float bv = bias ? b2f(bias[col]) : 0.0f;
#pragma unroll
      for (int r = 0; r < 4; ++r) {
        int row = n0 + wr * 64 + ti * 16 + ((lane >> 4) << 2) + r;
        if (row < NN) {
          float v = acc[ti][tj][r] + bv;
          if (RELU) v = fmaxf(v, 0.0f);
          if (F32OUT) outF[(size_t)row * J + col] = v;
          else        outB[(size_t)row * J + col] = f2b(v);
        }
      }
    }
}

// ---------------------------------------------------------------------------
// Fused lin2+lin3+lin4 (R10-verified): B = [lin2_w ; lin4_w], bias = [b2;b4].
// cols<256: x1 in registers -> dot w3 -> atomic out1acc.  cols>=256: x2 ->
// bf16 x2v.  Grid (4, 79).
// ---------------------------------------------------------------------------
__global__ __launch_bounds__(256, 2)
void gemm_fused234_kernel(const u16* __restrict__ A, const u16* __restrict__ B,
                          const u16* __restrict__ bias, const u16* __restrict__ w3,
                          float* __restrict__ out1acc, u16* __restrict__ x2v, int NN) {
  __shared__ u16 lA[128 * 64];
  __shared__ u16 lB[128 * 64];
  int lane = threadIdx.x & 63;
  int w = threadIdx.x >> 6;
  int wr = w >> 1, wc = w & 1;
  int n0 = blockIdx.y * 128;
  int j0 = blockIdx.x * 128;
  f32x4 acc[4][4];
#pragma unroll
  for (int i = 0; i < 4; ++i)
#pragma unroll
    for (int j = 0; j < 4; ++j) acc[i][j] = (f32x4){0.f, 0.f, 0.f, 0.f};

  for (int kt = 0; kt < 256; kt += 64) {
    stage_async(A, 256, n0, NN - 1, kt, lA, w, lane);
    stage_async(B, 256, j0, 511, kt, lB, w, lane);
    __syncthreads();
    mma_tile(lA, lB, acc, wr, wc, lane);
    __syncthreads();
  }

  if (j0 < 256) {
    float part[4][4];
#pragma unroll
    for (int ti = 0; ti < 4; ++ti)
#pragma unroll
      for (int r = 0; r < 4; ++r) part[ti][r] = 0.0f;
#pragma unroll
    for (int ti = 0; ti < 4; ++ti)
#pragma unroll
      for (int tj = 0; tj < 4; ++tj) {
        int col = j0 + wc * 64 + tj * 16 + (lane & 15);
        float bv = b2f(bias[col]);
        float wv = b2f(w3[col]);
#pragma unroll
        for (int r = 0; r < 4; ++r) {
          float v = fmaxf(acc[ti][tj][r] + bv, 0.0f);
          part[ti][r] += v * wv;
        }
      }
#pragma unroll
    for (int ti = 0; ti < 4; ++ti)
#pragma unroll
      for (int r = 0; r < 4; ++r) {
        float s = part[ti][r];
        s += __shfl_xor(s, 1);
        s += __shfl_xor(s, 2);
        s += __shfl_xor(s, 4);
        s += __shfl_xor(s, 8);
        if ((lane & 15) == 0) {
          int row = n0 + wr * 64 + ti * 16 + ((lane >> 4) << 2) + r;
          if (row < NN) unsafeAtomicAdd(&out1acc[row], s);
        }
      }
  } else {
#pragma unroll
    for (int ti = 0; ti < 4; ++ti)
#pragma unroll
      for (int tj = 0; tj < 4; ++tj) {
        int col = j0 + wc * 64 + tj * 16 + (lane & 15);
        float bv = b2f(bias[col]);
#pragma unroll
        for (int r = 0; r < 4; ++r) {
          int row = n0 + wr * 64 + ti * 16 + ((lane >> 4) << 2) + r;
          if (row < NN) {
            float v = fmaxf(acc[ti][tj][r] + bv, 0.0f);
            x2v[(size_t)row * 256 + (col - 256)] = f2b(v);
          }
        }
      }
  }
}

// ---------------------------------------------------------------------------
// Bilinear (R9-verified, 211 µs): A = x2v [N,256], B = bilin_w [16384,256];
// grid (128 j-slabs fast, 79 n-slabs slow) — R5-verified cache-optimal.
// Epilogue xv snapshotted from lA during the k-iter that holds it.
// ---------------------------------------------------------------------------
__global__ __launch_bounds__(256, 2)
void bilinear_kernel(const u16* __restrict__ x2v, const u16* __restrict__ W,
                     float* __restrict__ out2acc, int NN) {
  __shared__ u16 lA[128 * 64];
  __shared__ u16 lB[128 * 64];
  int lane = threadIdx.x & 63;
  int w = threadIdx.x >> 6;
  int wr = w >> 1, wc = w & 1;
  int n0 = blockIdx.y * 128;
  int rm0 = blockIdx.x * 128;
  int m0g = rm0 & 255;
  int xv_kt = (m0g >> 6) + wc;      // the k-tile holding this wave's xv values
  f32x4 acc[4][4];
#pragma unroll
  for (int i = 0; i < 4; ++i)
#pragma unroll
    for (int j = 0; j < 4; ++j) acc[i][j] = (f32x4){0.f, 0.f, 0.f, 0.f};

  u16 xvr[4][16];   // [tj][ti*4+r] snapshot of x2v[n, mg]

#pragma unroll
  for (int kt4 = 0; kt4 < 4; ++kt4) {
    stage_async(x2v, 256, n0, NN - 1, kt4 * 64, lA, w, lane);
    stage_async(W, 256, rm0, 16383, kt4 * 64, lB, w, lane);
    __syncthreads();
    mma_tile(lA, lB, acc, wr, wc, lane);
    if (kt4 == xv_kt) {             // wave-uniform branch; lA valid until barrier
#pragma unroll
      for (int tj = 0; tj < 4; ++tj) {
        int kl = tj * 16 + (lane & 15);
        int ch = kl >> 3, off = kl & 7;
#pragma unroll
        for (int ti = 0; ti < 4; ++ti)
#pragma unroll
          for (int r = 0; r < 4; ++r) {
            int rowl = wr * 64 + ti * 16 + ((lane >> 4) << 2) + r;
            xvr[tj][ti * 4 + r] = lA[rowl * 64 + ((ch ^ (rowl & 7)) * 8) + off];
          }
      }
    }
    __syncthreads();
  }

  int region = rm0 >> 8;
  float rowsum[4][4];
#pragma unroll
  for (int ti = 0; ti < 4; ++ti)
#pragma unroll
    for (int r = 0; r < 4; ++r) rowsum[ti][r] = 0.0f;

#pragma unroll
  for (int ti = 0; ti < 4; ++ti)
#pragma unroll
    for (int tj = 0; tj < 4; ++tj)
#pragma unroll
      for (int r = 0; r < 4; ++r)
        rowsum[ti][r] += acc[ti][tj][r] * b2f(xvr[tj][ti * 4 + r]);

#pragma unroll
  for (int ti = 0; ti < 4; ++ti)
#pragma unroll
    for (int r = 0; r < 4; ++r) {
      float s = rowsum[ti][r];
      s += __shfl_xor(s, 1);
      s += __shfl_xor(s, 2);
      s += __shfl_xor(s, 4);
      s += __shfl_xor(s, 8);
      if ((lane & 15) == 0) {
        int rowl = wr * 64 + ti * 16 + ((lane >> 4) << 2) + r;
        int n = n0 + rowl;
        if (n < NN) unsafeAtomicAdd(&out2acc[(size_t)n * 64 + region], s);
      }
    }
}

// --------------------- edge sort (counting) + gather ------------------------
__global__ void hist_kernel(const int* __restrict__ ei, int* __restrict__ count) {
  int i = blockIdx.x * 256 + threadIdx.x;
  if (i < E_EDGES) atomicAdd(&count[ei[E_EDGES + i]], 1);
}

// shuffle-based scan (R11-verified, ~11 µs tail win)
__global__ void scan_kernel(const int* __restrict__ count, int* __restrict__ start,
                            int* __restrict__ cursor, float* __restrict__ dinv) {
  __shared__ int wsum[16];
  __shared__ int carry_s;
  int t = threadIdx.x;          // 1024 threads = 16 waves
  int wv = t >> 6, ln = t & 63;
  if (t == 0) carry_s = 0;
  __syncthreads();
  for (int base = 0; base < N_NODES; base += 1024) {
    int i = base + t;
    int v = (i < N_NODES) ? count[i] : 0;
    int s = v;
#pragma unroll
    for (int o = 1; o < 64; o <<= 1) {
      int u = __shfl_up(s, o);
      if (ln >= o) s += u;
    }
    if (ln == 63) wsum[wv] = s;
    __syncthreads();
    if (wv == 0) {
      int x = (ln < 16) ? wsum[ln] : 0;
#pragma unroll
      for (int o = 1; o < 16; o <<= 1) {
        int u = __shfl_up(x, o);
        if (ln >= o) x += u;
      }
      if (ln < 16) wsum[ln] = x;
    }
    __syncthreads();
    int excl = s - v + (wv ? wsum[wv - 1] : 0) + carry_s;
    if (i < N_NODES) {
      start[i] = excl;
      cursor[i] = excl;
      dinv[i] = rsqrtf(1.0f + (float)v);
    }
    __syncthreads();
    if (t == 0) carry_s += wsum[15];
    __syncthreads();
  }
}

__global__ void place_kernel(const int* __restrict__ ei, int* __restrict__ cursor,
                             int* __restrict__ order) {
  int i = blockIdx.x * 256 + threadIdx.x;
  if (i >= E_EDGES) return;
  int d = ei[E_EDGES + i];
  int pos = atomicAdd(&cursor[d], 1);
  order[pos] = i;
}

__global__ void gather_kernel(const int* __restrict__ ei, const int* __restrict__ order,
                              const int* __restrict__ start, const int* __restrict__ count,
                              const float* __restrict__ dinv, const float* __restrict__ xw,
                              const u16* __restrict__ conv_b, const u16* __restrict__ x,
                              u16* __restrict__ x0) {
  int node = (blockIdx.x * blockDim.x + threadIdx.x) >> 6;
  int lane = threadIdx.x & 63;
  if (node >= N_NODES) return;
  int s0 = start[node], cnt = count[node];
  float dn = dinv[node];
  float ax = 0.f, ay = 0.f, az = 0.f, aw = 0.f;
  for (int base = 0; base < cnt; base += 64) {
    int rem = cnt - base;
    int m = rem < 64 ? rem : 64;
    int eid = (lane < m) ? order[s0 + base + lane] : 0;
    int s = (lane < m) ? ei[eid] : 0;
    float nrm = (lane < m) ? dinv[s] * dn : 0.f;
    for (int j = 0; j < m; ++j) {
      int sj = __shfl(s, j);
      float nj = __shfl(nrm, j);
      float4 v = *((const float4*)(xw + (size_t)sj * 256) + lane);
      ax += nj * v.x; ay += nj * v.y; az += nj * v.z; aw += nj * v.w;
    }
  }
  float4 sv = *((const float4*)(xw + (size_t)node * 256) + lane);
  float slw = dn * dn;
  const u16* bb = conv_b + lane * 4;
  const u16* xr = x + (size_t)node * 256 + lane * 4;
  u16 o[4];
  float vals[4] = {ax + slw * sv.x, ay + slw * sv.y, az + slw * sv.z, aw + slw * sv.w};
#pragma unroll
  for (int j = 0; j < 4; ++j) {
    float v = vals[j] + b2f(bb[j]);
    v = fmaxf(v, 0.0f) + b2f(xr[j]);
    o[j] = f2b(v);
  }
  *((ushort4*)(x0 + (size_t)node * 256) + lane) = make_ushort4(o[0], o[1], o[2], o[3]);
}

// ------------------------------- final output -------------------------------
__global__ void out_final_kernel(const float* __restrict__ out1acc,
                                 const float* __restrict__ out2acc,
                                 const u16* __restrict__ b3, const u16* __restrict__ bb,
                                 void* __restrict__ dout, const int* __restrict__ flag) {
  int idx = blockIdx.x * 256 + threadIdx.x;
  int f = *flag;
  if (idx < N_NODES) {
    float v = out1acc[idx] + b2f(b3[0]);
    if (f) ((u16*)dout)[idx] = f2b(v);
    else   ((float*)dout)[idx] = v;
  } else if (idx < N_NODES + N_NODES * 64) {
    int k = idx - N_NODES;
    float v = out2acc[k] + b2f(bb[k & 63]);
    if (f) ((u16*)dout)[idx] = f2b(v);
    else   ((float*)dout)[idx] = v;
  }
}

// ----------------------------------------------------------------------------
extern "C" void kernel_launch(void* const* d_in, const int* in_sizes, int n_in,
                              void* d_out, int out_size, void* d_ws, size_t ws_size,
                              hipStream_t stream) {
  const int* ei = (const int*)d_in[1];

  float* ws      = (float*)d_ws;
  float* xw      = ws;                          // [N,256] f32
  int*   count   = (int*)(xw + N_NODES * 256);  // [N]
  int*   start   = count + 10240;               // [N]
  int*   cursor  = start + 10240;               // [N]
  int*   order   = cursor + 10240;              // [E]
  float* dinv    = (float*)(order + E_EDGES);   // [N]
  float* out1acc = dinv + 10240;                // [N] (padded 10240)
  float* out2acc = out1acc + 10240;             // [N,64] (adjacent: one memset)
  u16* x0  = (u16*)(out2acc + N_NODES * 64);    // [N,256] bf16
  u16* x0m = x0 + N_NODES * 256;
  u16* x2v = x0m + N_NODES * 256;
  u16* cx  = x2v + N_NODES * 256;               // canonical bf16 inputs
  u16* cwc = cx + N_NODES * 256;
  u16* cw1 = cwc + 65536;
  u16* cw2 = cw1 + 65536;                       // cw2, cw4 contiguous = [512,256]
  u16* cw4 = cw2 + 65536;
  u16* cwB = cw4 + 65536;
  u16* cbc = cwB + 4194304;
  u16* cb1 = cbc + 256;
  u16* cb2 = cb1 + 256;                         // cb2, cb4 contiguous = [512]
  u16* cb4 = cb2 + 256;
  u16* cw3 = cb4 + 256;
  u16* cbB = cw3 + 256;
  u16* cb3 = cbB + 64;
  int* flag = (int*)(cb3 + 16);

  hipMemsetAsync(count, 0, N_NODES * sizeof(int), stream);
  hipMemsetAsync(out1acc, 0, (10240 + (size_t)N_NODES * 64) * sizeof(float), stream);

  detect_kernel<<<1, 64, 0, stream>>>((const unsigned*)d_in[0], flag);

  canon_kernel<<<(N_NODES * 256 + 255) / 256, 256, 0, stream>>>(d_in[0], cx, N_NODES * 256, flag);
  canon4_kernel<<<1024, 256, 0, stream>>>(d_in[2], d_in[4], d_in[6], d_in[10],
                                          cwc, cw1, cw2, cw4, flag);
  canon_small_kernel<<<1, 256, 0, stream>>>(d_in[3], d_in[5], d_in[7], d_in[11],
                                            d_in[8], d_in[13], d_in[9],
                                            cbc, cb1, cb2, cb4, cw3, cbB, cb3, flag);
  canon_kernel<<<(4194304 + 255) / 256, 256, 0, stream>>>(d_in[12], cwB, 4194304, flag);

  hist_kernel<<<(E_EDGES + 255) / 256, 256, 0, stream>>>(ei, count);
  scan_kernel<<<1, 1024, 0, stream>>>(count, start, cursor, dinv);
  place_kernel<<<(E_EDGES + 255) / 256, 256, 0, stream>>>(ei, cursor, order);

  gemm_kernel<false, true><<<dim3(2, 79), 256, 0, stream>>>(
      cx, cwc, nullptr, xw, nullptr, N_NODES, 256, 256);

  gather_kernel<<<(N_NODES * 64 + 255) / 256, 256, 0, stream>>>(
      ei, order, start, count, dinv, xw, cbc, cx, x0);

  gemm_kernel<true, false><<<dim3(2, 79), 256, 0, stream>>>(
      x0, cw1, cb1, nullptr, x0m, N_NODES, 256, 256);

  gemm_fused234_kernel<<<dim3(4, 79), 256, 0, stream>>>(
      x0m, cw2, cb2, cw3, out1acc, x2v, N_NODES);

  bilinear_kernel<<<dim3(128, 79), 256, 0, stream>>>(x2v, cwB, out2acc, N_NODES);

  out_final_kernel<<<(N_NODES * 65 + 255) / 256, 256, 0, stream>>>(
      out1acc, out2acc, cb3, cbB, d_out, flag);
}